// Round 1
// baseline (18643.710 us; speedup 1.0000x reference)
//
#include <hip/hip_runtime.h>
#include <hip/hip_bf16.h>

#define BATCH 128
#define SEQ   1024
#define INDIM 256
#define HID   1024
#define NGATE 4096   // 4*HID
#define KTOT  1280   // INDIM + HID
#define OUTD  256

typedef __attribute__((ext_vector_type(8))) short s16x8;
typedef __attribute__((ext_vector_type(4))) float f32x4;

__device__ __forceinline__ unsigned short f2bf(float f) {
    unsigned int u = __float_as_uint(f);
    u += 0x7FFFu + ((u >> 16) & 1u);   // round-to-nearest-even
    return (unsigned short)(u >> 16);
}
__device__ __forceinline__ float bf2f(unsigned short s) {
    return __uint_as_float(((unsigned int)s) << 16);
}
__device__ __forceinline__ float sigmoidf_(float x) {
    return 1.0f / (1.0f + __expf(-x));
}
__device__ __forceinline__ float tanhf_(float x) {
    // stable: x->+inf => 1, x->-inf => -1
    return 1.0f - 2.0f / (1.0f + __expf(2.0f * x));
}

// ---------------------------------------------------------------------------
// Prep 1: WT[n][k] bf16, n in [0,4096) gate-columns, k in [0,1280):
//         k<256 -> Wx[k][n], else Wh[k-256][n].  (transpose via LDS tiles)
// grid: (KTOT/64=20, NGATE/64=64), block 256
// ---------------------------------------------------------------------------
__global__ __launch_bounds__(256) void prep_wt(const float* __restrict__ Wx,
                                               const float* __restrict__ Wh,
                                               unsigned short* __restrict__ WT) {
    __shared__ float tile[64][65];
    int k0 = blockIdx.x * 64;
    int n0 = blockIdx.y * 64;
    for (int idx = threadIdx.x; idx < 64 * 64; idx += 256) {
        int kk = idx >> 6, nn = idx & 63;
        int k = k0 + kk;
        float v = (k < INDIM) ? Wx[(size_t)k * NGATE + (n0 + nn)]
                              : Wh[(size_t)(k - INDIM) * NGATE + (n0 + nn)];
        tile[kk][nn] = v;
    }
    __syncthreads();
    for (int idx = threadIdx.x; idx < 64 * 64; idx += 256) {
        int nn = idx >> 6, kk = idx & 63;
        WT[(size_t)(n0 + nn) * KTOT + (k0 + kk)] = f2bf(tile[kk][nn]);
    }
}

// ---------------------------------------------------------------------------
// Prep 2: x (fp32) -> xb (bf16), and zero h0 (bf16) + c (fp32)
// grid: 1024 blocks x 256
// ---------------------------------------------------------------------------
__global__ __launch_bounds__(256) void prep_x(const float* __restrict__ x,
                                              unsigned short* __restrict__ xb,
                                              unsigned short* __restrict__ h0,
                                              float* __restrict__ c) {
    int gid = blockIdx.x * blockDim.x + threadIdx.x;
    int stride = gridDim.x * blockDim.x;
    const int N4 = BATCH * SEQ * INDIM / 4;
    const float4* xv = reinterpret_cast<const float4*>(x);
    uint2* xo = reinterpret_cast<uint2*>(xb);
    for (int i = gid; i < N4; i += stride) {
        float4 v = xv[i];
        uint2 o;
        o.x = (unsigned)f2bf(v.x) | ((unsigned)f2bf(v.y) << 16);
        o.y = (unsigned)f2bf(v.z) | ((unsigned)f2bf(v.w) << 16);
        xo[i] = o;
    }
    const int NH = BATCH * HID;
    for (int i = gid; i < NH; i += stride) {
        h0[i] = 0;
        c[i] = 0.0f;
    }
}

// ---------------------------------------------------------------------------
// Fused LSTM step t: gates = [x_t | h_in] @ WT^T (+bias in epilogue),
// activations, c update, h_out.  One WG = 32 batch rows x 16 h-cols (x4 gates).
// grid: dim3(64, 4)  (x = n-slice, y = m-tile), block 256 (4 waves)
// ---------------------------------------------------------------------------
__global__ __launch_bounds__(256) void lstm_step(
    const unsigned short* __restrict__ xb,    // [B][S][INDIM] bf16
    const unsigned short* __restrict__ WT,    // [NGATE][KTOT] bf16
    const unsigned short* __restrict__ h_in,  // [B][HID] bf16
    unsigned short* __restrict__ h_out,       // [B][HID] bf16
    float* __restrict__ c,                    // [B][HID] fp32 (in/out)
    const float* __restrict__ bias,           // [NGATE]
    int t) {
    __shared__ float glds[8 * 256];  // [mf2][gate4][row16][col16]
    int tid = threadIdx.x;
    int wave = tid >> 6, lane = tid & 63;
    int mf = wave & 1, nfp = wave >> 1;
    int g0 = 2 * nfp, g1 = g0 + 1;
    int b0 = blockIdx.y * 32;
    int j0 = blockIdx.x * 16;
    int lr = lane & 15;   // A-row / B-col within tile
    int kq = lane >> 4;   // 0..3 (k-quarter, 8 elems each)
    int ar = b0 + mf * 16 + lr;

    const unsigned short* ax = xb + ((size_t)ar * SEQ + t) * INDIM + kq * 8;
    const unsigned short* ah = h_in + (size_t)ar * HID + kq * 8;
    const unsigned short* bp0 = WT + ((size_t)(g0 * HID + j0 + lr)) * KTOT + kq * 8;
    const unsigned short* bp1 = WT + ((size_t)(g1 * HID + j0 + lr)) * KTOT + kq * 8;

    f32x4 acc0 = {0.f, 0.f, 0.f, 0.f};
    f32x4 acc1 = {0.f, 0.f, 0.f, 0.f};

    // K part 1: x_t contribution, k = 0..255 (8 MFMA k-steps)
#pragma unroll 4
    for (int kk = 0; kk < 8; kk++) {
        s16x8 a  = *reinterpret_cast<const s16x8*>(ax + kk * 32);
        s16x8 b0v = *reinterpret_cast<const s16x8*>(bp0 + kk * 32);
        s16x8 b1v = *reinterpret_cast<const s16x8*>(bp1 + kk * 32);
        acc0 = __builtin_amdgcn_mfma_f32_16x16x32_bf16(a, b0v, acc0, 0, 0, 0);
        acc1 = __builtin_amdgcn_mfma_f32_16x16x32_bf16(a, b1v, acc1, 0, 0, 0);
    }
    // K part 2: h contribution, k = 256..1279 (32 MFMA k-steps)
#pragma unroll 4
    for (int kk = 8; kk < 40; kk++) {
        s16x8 a  = *reinterpret_cast<const s16x8*>(ah + kk * 32 - 256);
        s16x8 b0v = *reinterpret_cast<const s16x8*>(bp0 + kk * 32);
        s16x8 b1v = *reinterpret_cast<const s16x8*>(bp1 + kk * 32);
        acc0 = __builtin_amdgcn_mfma_f32_16x16x32_bf16(a, b0v, acc0, 0, 0, 0);
        acc1 = __builtin_amdgcn_mfma_f32_16x16x32_bf16(a, b1v, acc1, 0, 0, 0);
    }

    // C/D layout: col = lane&15, row = (lane>>4)*4 + reg  [verified m89]
#pragma unroll
    for (int r = 0; r < 4; r++) {
        int row = kq * 4 + r;
        glds[((mf * 4 + g0) << 8) + (row << 4) + lr] = acc0[r];
        glds[((mf * 4 + g1) << 8) + (row << 4) + lr] = acc1[r];
    }
    __syncthreads();

    // Epilogue: 512 (row,col) cells, 2 per thread
#pragma unroll
    for (int e = tid; e < 512; e += 256) {
        int emf = e >> 8;
        int rc = e & 255;
        int col = rc & 15;
        int row_g = b0 + emf * 16 + (rc >> 4);
        int j = j0 + col;
        float gf = glds[((emf * 4 + 0) << 8) + rc] + bias[0 * HID + j];
        float gi = glds[((emf * 4 + 1) << 8) + rc] + bias[1 * HID + j];
        float gg = glds[((emf * 4 + 2) << 8) + rc] + bias[2 * HID + j];
        float go = glds[((emf * 4 + 3) << 8) + rc] + bias[3 * HID + j];
        float f = sigmoidf_(gf);
        float i = sigmoidf_(gi);
        float g = tanhf_(gg);
        float o = sigmoidf_(go);
        size_t ci = (size_t)row_g * HID + j;
        float cn = f * c[ci] + i * g;
        c[ci] = cn;
        h_out[ci] = f2bf(o * tanhf_(cn));
    }
}

// ---------------------------------------------------------------------------
// Final FC: out[b][o] = sum_k h[b][k]*Wfc[k][o] + bfc[o]   (fp32 vector)
// grid 128, block 256
// ---------------------------------------------------------------------------
__global__ __launch_bounds__(256) void final_fc(const unsigned short* __restrict__ h,
                                                const float* __restrict__ Wfc,
                                                const float* __restrict__ bfc,
                                                float* __restrict__ out) {
    int b = blockIdx.x;
    int o = threadIdx.x;
    const unsigned short* hr = h + (size_t)b * HID;
    float acc = bfc[o];
#pragma unroll 8
    for (int k = 0; k < HID; k++) {
        acc += bf2f(hr[k]) * Wfc[(size_t)k * OUTD + o];
    }
    out[(size_t)b * OUTD + o] = acc;
}

// ---------------------------------------------------------------------------
extern "C" void kernel_launch(void* const* d_in, const int* in_sizes, int n_in,
                              void* d_out, int out_size, void* d_ws, size_t ws_size,
                              hipStream_t stream) {
    const float* x    = (const float*)d_in[0];
    const float* Wx   = (const float*)d_in[1];
    const float* Wh   = (const float*)d_in[2];
    const float* bias = (const float*)d_in[3];
    const float* Wfc  = (const float*)d_in[4];
    const float* bfc  = (const float*)d_in[5];
    float* out = (float*)d_out;

    char* ws = (char*)d_ws;
    // ws layout (bytes):
    //   WT : 4096*1280*2      = 10,485,760
    //   xb : 128*1024*256*2   = 67,108,864
    //   h0 : 128*1024*2       =    262,144
    //   h1 : 128*1024*2       =    262,144
    //   c  : 128*1024*4       =    524,288   -> total 78,643,200
    unsigned short* WT = (unsigned short*)(ws);
    unsigned short* xb = (unsigned short*)(ws + 10485760);
    unsigned short* h0 = (unsigned short*)(ws + 77594624);
    unsigned short* h1 = (unsigned short*)(ws + 77856768);
    float* c           = (float*)(ws + 78118912);

    hipLaunchKernelGGL(prep_wt, dim3(KTOT / 64, NGATE / 64), dim3(256), 0, stream,
                       Wx, Wh, WT);
    hipLaunchKernelGGL(prep_x, dim3(1024), dim3(256), 0, stream, x, xb, h0, c);

    unsigned short* hb[2] = {h0, h1};
    for (int t = 0; t < SEQ; t++) {
        hipLaunchKernelGGL(lstm_step, dim3(64, 4), dim3(256), 0, stream,
                           xb, WT, hb[t & 1], hb[(t + 1) & 1], c, bias, t);
    }
    // final h is in h0 (1024 steps -> even parity)
    hipLaunchKernelGGL(final_fc, dim3(128), dim3(256), 0, stream, h0, Wfc, bfc, out);
}

// Round 2
// 16084.355 us; speedup vs baseline: 1.1591x; 1.1591x over previous
//
#include <hip/hip_runtime.h>
#include <hip/hip_bf16.h>

#define BATCH 128
#define SEQ   1024
#define INDIM 256
#define HID   1024
#define NGATE 4096   // 4*HID
#define KTOT  1280   // INDIM + HID
#define OUTD  256
#define NKK   40     // K-steps of 32 (1280/32)
#define XKK   8      // k-steps covering the x part (256/32)
#define NBG   8      // batch groups
#define ROWS  16     // batch rows per group
#define NSL   32     // column-slice WGs per group
#define JCOLS 32     // h-columns per WG

typedef __attribute__((ext_vector_type(8))) short s16x8;
typedef __attribute__((ext_vector_type(4))) float f32x4;

__device__ __forceinline__ unsigned short f2bf(float f) {
    unsigned int u = __float_as_uint(f);
    u += 0x7FFFu + ((u >> 16) & 1u);   // round-to-nearest-even
    return (unsigned short)(u >> 16);
}
__device__ __forceinline__ float sigmoidf_(float x) {
    return 1.0f / (1.0f + __expf(-x));
}
__device__ __forceinline__ float tanhf_(float x) {
    return 1.0f - 2.0f / (1.0f + __expf(2.0f * x));
}

// ---------------------------------------------------------------------------
// Prep 1: WT[n][k] bf16, n in [0,4096) gate-cols, k in [0,1280):
//         k<256 -> Wx[k][n], else Wh[k-256][n].
// grid (20, 64), block 256
// ---------------------------------------------------------------------------
__global__ __launch_bounds__(256) void prep_wt(const float* __restrict__ Wx,
                                               const float* __restrict__ Wh,
                                               unsigned short* __restrict__ WT) {
    __shared__ float tile[64][65];
    int k0 = blockIdx.x * 64;
    int n0 = blockIdx.y * 64;
    for (int idx = threadIdx.x; idx < 64 * 64; idx += 256) {
        int kk = idx >> 6, nn = idx & 63;
        int k = k0 + kk;
        float v = (k < INDIM) ? Wx[(size_t)k * NGATE + (n0 + nn)]
                              : Wh[(size_t)(k - INDIM) * NGATE + (n0 + nn)];
        tile[kk][nn] = v;
    }
    __syncthreads();
    for (int idx = threadIdx.x; idx < 64 * 64; idx += 256) {
        int nn = idx >> 6, kk = idx & 63;
        WT[(size_t)(n0 + nn) * KTOT + (k0 + kk)] = f2bf(tile[kk][nn]);
    }
}

// ---------------------------------------------------------------------------
// Prep 2: x fp32 -> bf16, zero h0, zero barrier counters
// ---------------------------------------------------------------------------
__global__ __launch_bounds__(256) void prep_x(const float* __restrict__ x,
                                              unsigned short* __restrict__ xb,
                                              unsigned short* __restrict__ h0,
                                              unsigned int* __restrict__ cnt) {
    int gid = blockIdx.x * blockDim.x + threadIdx.x;
    int stride = gridDim.x * blockDim.x;
    const int N4 = BATCH * SEQ * INDIM / 4;
    const float4* xv = reinterpret_cast<const float4*>(x);
    uint2* xo = reinterpret_cast<uint2*>(xb);
    for (int i = gid; i < N4; i += stride) {
        float4 v = xv[i];
        uint2 o;
        o.x = (unsigned)f2bf(v.x) | ((unsigned)f2bf(v.y) << 16);
        o.y = (unsigned)f2bf(v.z) | ((unsigned)f2bf(v.w) << 16);
        xo[i] = o;
    }
    const int NH = BATCH * HID;
    for (int i = gid; i < NH; i += stride) h0[i] = 0;
    if (gid < NBG) cnt[gid] = 0;
}

// ---------------------------------------------------------------------------
// Persistent LSTM: 256 WGs x 256 threads. WG = (bg, ns): batch rows
// bg*16..+16, h-cols ns*32..+32 (all 4 gates). Wave w = gate w, tile 16x32.
// B-fragments (40 k-steps x 2 n-tiles) live in registers for all 1024 steps.
// One group-local (32 WG) barrier per step; h double-buffered.
// ---------------------------------------------------------------------------
__global__ __launch_bounds__(256, 1) void lstm_persist(
    const unsigned short* __restrict__ xb,   // [B][S][INDIM] bf16
    const unsigned short* __restrict__ WT,   // [NGATE][KTOT] bf16
    unsigned short* __restrict__ h0,         // [B][HID] bf16 (zeroed)
    unsigned short* __restrict__ h1,         // [B][HID] bf16
    unsigned int* __restrict__ cnt,          // [NBG] barrier counters (zeroed)
    const float* __restrict__ bias) {        // [NGATE]

    __shared__ unsigned short Abuf[NKK * 512];   // [kk][row16][k32], 40 KB
    __shared__ float gex[4 * ROWS * JCOLS];      // [gate][row][col], 8 KB

    const int tid  = threadIdx.x;
    const int wave = tid >> 6, lane = tid & 63;
    const int lr = lane & 15, kq = lane >> 4;
    const int bg = blockIdx.x & 7;           // XCD-aligned group
    const int ns = blockIdx.x >> 3;          // 0..31
    const int b0 = bg * ROWS;
    const int j0 = ns * JCOLS;

    // ---- B fragments into registers (gate=wave, cols j0..j0+31, full K) ----
    s16x8 b0r[NKK], b1r[NKK];
    {
        const unsigned short* base0 =
            WT + ((size_t)(wave * HID + j0 + lr)) * KTOT + kq * 8;
        const unsigned short* base1 = base0 + (size_t)16 * KTOT;
#pragma unroll
        for (int kk = 0; kk < NKK; kk++) {
            b0r[kk] = *reinterpret_cast<const s16x8*>(base0 + kk * 32);
            b1r[kk] = *reinterpret_cast<const s16x8*>(base1 + kk * 32);
        }
    }

    // ---- epilogue constants: thread handles cells (erow0,ecol),(erow1,ecol)
    const int ecol = tid & 31, erow0 = tid >> 5, erow1 = erow0 + 8;
    const int j = j0 + ecol;
    const float bf = bias[0 * HID + j], bi = bias[1 * HID + j],
                bgg = bias[2 * HID + j], bo = bias[3 * HID + j];
    float c0 = 0.f, c1 = 0.f;

    // ---- staging source addressing: lane l -> row l>>2, k-quarter l&3 ----
    const int srow = lane >> 2, skq = lane & 3;
    const unsigned short* xsrc =
        xb + (size_t)(b0 + srow) * SEQ * INDIM + skq * 8;
    const size_t hoff = (size_t)(b0 + srow) * HID + skq * 8;

    unsigned int* mycnt = cnt + bg;

    for (int t = 0; t < SEQ; t++) {
        const unsigned short* hin = (t & 1) ? h1 : h0;
        unsigned short* hout      = (t & 1) ? h0 : h1;

        // ---- stage A = [x_t | h] into LDS, wave w covers kk = w*10..+9 ----
#pragma unroll
        for (int i = 0; i < 10; i++) {
            int kk = wave * 10 + i;
            const unsigned short* g =
                (kk < XKK) ? (xsrc + (size_t)t * INDIM + kk * 32)
                           : (hin + hoff + (size_t)(kk - XKK) * 32);
            __builtin_amdgcn_global_load_lds(
                (const __attribute__((address_space(1))) void*)g,
                (__attribute__((address_space(3))) void*)(&Abuf[kk * 512]),
                16, 0, 0);
        }
        __syncthreads();

        // ---- MFMA: 40 k-steps, B from registers ----
        f32x4 acc0 = {0.f, 0.f, 0.f, 0.f};
        f32x4 acc1 = {0.f, 0.f, 0.f, 0.f};
        const unsigned short* ap = &Abuf[lr * 32 + kq * 8];
#pragma unroll
        for (int kk = 0; kk < NKK; kk++) {
            s16x8 a = *reinterpret_cast<const s16x8*>(ap + kk * 512);
            acc0 = __builtin_amdgcn_mfma_f32_16x16x32_bf16(a, b0r[kk], acc0, 0, 0, 0);
            acc1 = __builtin_amdgcn_mfma_f32_16x16x32_bf16(a, b1r[kk], acc1, 0, 0, 0);
        }

        // ---- exchange gates via LDS (C/D: col=lane&15, row=(lane>>4)*4+r) --
#pragma unroll
        for (int r = 0; r < 4; r++) {
            int row = kq * 4 + r;
            gex[wave * 512 + row * 32 + lr]      = acc0[r];
            gex[wave * 512 + row * 32 + 16 + lr] = acc1[r];
        }
        __syncthreads();

        // ---- activations + c update + h store (2 cells/thread) ----
        {
            float ff = sigmoidf_(gex[0 * 512 + erow0 * 32 + ecol] + bf);
            float ii = sigmoidf_(gex[1 * 512 + erow0 * 32 + ecol] + bi);
            float gg = tanhf_(gex[2 * 512 + erow0 * 32 + ecol] + bgg);
            float oo = sigmoidf_(gex[3 * 512 + erow0 * 32 + ecol] + bo);
            c0 = ff * c0 + ii * gg;
            hout[(size_t)(b0 + erow0) * HID + j] = f2bf(oo * tanhf_(c0));
        }
        {
            float ff = sigmoidf_(gex[0 * 512 + erow1 * 32 + ecol] + bf);
            float ii = sigmoidf_(gex[1 * 512 + erow1 * 32 + ecol] + bi);
            float gg = tanhf_(gex[2 * 512 + erow1 * 32 + ecol] + bgg);
            float oo = sigmoidf_(gex[3 * 512 + erow1 * 32 + ecol] + bo);
            c1 = ff * c1 + ii * gg;
            hout[(size_t)(b0 + erow1) * HID + j] = f2bf(oo * tanhf_(c1));
        }

        // ---- group barrier (32 WGs): release-fence, add, spin, acquire ----
        __syncthreads();   // all h stores issued+drained, gex reads done
        if (tid == 0) {
            __threadfence();                                   // release
            __hip_atomic_fetch_add(mycnt, 1u, __ATOMIC_RELAXED,
                                   __HIP_MEMORY_SCOPE_AGENT);
            unsigned target = (unsigned)(t + 1) * NSL;
            while (__hip_atomic_load(mycnt, __ATOMIC_RELAXED,
                                     __HIP_MEMORY_SCOPE_AGENT) < target) {
                __builtin_amdgcn_s_sleep(1);
            }
            __threadfence();                                   // acquire
        }
        __syncthreads();
    }
}

// ---------------------------------------------------------------------------
// Final FC: out[b][o] = sum_k h[b][k]*Wfc[k][o] + bfc[o]
// ---------------------------------------------------------------------------
__global__ __launch_bounds__(256) void final_fc(const unsigned short* __restrict__ h,
                                                const float* __restrict__ Wfc,
                                                const float* __restrict__ bfc,
                                                float* __restrict__ out) {
    int b = blockIdx.x;
    int o = threadIdx.x;
    const unsigned short* hr = h + (size_t)b * HID;
    float acc = bfc[o];
#pragma unroll 8
    for (int k = 0; k < HID; k++) {
        acc += __uint_as_float(((unsigned)hr[k]) << 16) * Wfc[(size_t)k * OUTD + o];
    }
    out[(size_t)b * OUTD + o] = acc;
}

// ---------------------------------------------------------------------------
extern "C" void kernel_launch(void* const* d_in, const int* in_sizes, int n_in,
                              void* d_out, int out_size, void* d_ws, size_t ws_size,
                              hipStream_t stream) {
    const float* x    = (const float*)d_in[0];
    const float* Wx   = (const float*)d_in[1];
    const float* Wh   = (const float*)d_in[2];
    const float* bias = (const float*)d_in[3];
    const float* Wfc  = (const float*)d_in[4];
    const float* bfc  = (const float*)d_in[5];
    float* out = (float*)d_out;

    char* ws = (char*)d_ws;
    // ws layout (bytes):
    //   WT  : 4096*1280*2    = 10,485,760   @ 0
    //   xb  : 128*1024*256*2 = 67,108,864   @ 10,485,760
    //   h0  : 128*1024*2     =    262,144   @ 77,594,624
    //   h1  : 128*1024*2     =    262,144   @ 77,856,768
    //   cnt : 8*4                           @ 78,118,912
    unsigned short* WT = (unsigned short*)(ws);
    unsigned short* xb = (unsigned short*)(ws + 10485760);
    unsigned short* h0 = (unsigned short*)(ws + 77594624);
    unsigned short* h1 = (unsigned short*)(ws + 77856768);
    unsigned int* cnt  = (unsigned int*)(ws + 78118912);

    hipLaunchKernelGGL(prep_wt, dim3(KTOT / 64, NGATE / 64), dim3(256), 0, stream,
                       Wx, Wh, WT);
    hipLaunchKernelGGL(prep_x, dim3(1024), dim3(256), 0, stream, x, xb, h0, cnt);

    hipLaunchKernelGGL(lstm_persist, dim3(256), dim3(256), 0, stream,
                       xb, WT, h0, h1, cnt, bias);

    // 1024 steps -> final h lands in h0
    hipLaunchKernelGGL(final_fc, dim3(128), dim3(256), 0, stream, h0, Wfc, bfc, out);
}

// Round 3
// 3563.021 us; speedup vs baseline: 5.2326x; 4.5142x over previous
//
#include <hip/hip_runtime.h>
#include <hip/hip_bf16.h>

#define BATCH 128
#define SEQ   1024
#define INDIM 256
#define HID   1024
#define NGATE 4096   // 4*HID
#define KTOT  1280   // INDIM + HID
#define OUTD  256
#define NKK   40     // total K-steps of 32 (1280/32)
#define XKK   8      // k-steps covering the x part (256/32)
#define HKK   32     // k-steps covering the h part
#define NBG   8      // batch groups
#define ROWS  16     // batch rows per group
#define NSL   32     // WGs per group
#define JCOLS 32     // h-columns per WG

typedef __attribute__((ext_vector_type(8))) short s16x8;
typedef __attribute__((ext_vector_type(4))) float f32x4;

__device__ __forceinline__ unsigned short f2bf(float f) {
    unsigned int u = __float_as_uint(f);
    u += 0x7FFFu + ((u >> 16) & 1u);
    return (unsigned short)(u >> 16);
}
__device__ __forceinline__ float sigmoidf_(float x) {
    return 1.0f / (1.0f + __expf(-x));
}
__device__ __forceinline__ float tanhf_(float x) {
    return 1.0f - 2.0f / (1.0f + __expf(2.0f * x));
}

// LDS slot swizzle: slice holds 16 rows x 4 kq of 16B. slot p for (row,kq):
//   p = row*4 + ((kq + (row>>1)) & 3)   -> MFMA b128 reads are ~2-way (free)
// inverse (staging lane s writes slot s): row = s>>2, kq = ((s&3)-(s>>3))&3

// ---------------------------------------------------------------------------
// Prep 1: WT[n][k] bf16 (transposed, concatenated [Wx;Wh])
// ---------------------------------------------------------------------------
__global__ __launch_bounds__(256) void prep_wt(const float* __restrict__ Wx,
                                               const float* __restrict__ Wh,
                                               unsigned short* __restrict__ WT) {
    __shared__ float tile[64][65];
    int k0 = blockIdx.x * 64;
    int n0 = blockIdx.y * 64;
    for (int idx = threadIdx.x; idx < 64 * 64; idx += 256) {
        int kk = idx >> 6, nn = idx & 63;
        int k = k0 + kk;
        float v = (k < INDIM) ? Wx[(size_t)k * NGATE + (n0 + nn)]
                              : Wh[(size_t)(k - INDIM) * NGATE + (n0 + nn)];
        tile[kk][nn] = v;
    }
    __syncthreads();
    for (int idx = threadIdx.x; idx < 64 * 64; idx += 256) {
        int nn = idx >> 6, kk = idx & 63;
        WT[(size_t)(n0 + nn) * KTOT + (k0 + kk)] = f2bf(tile[kk][nn]);
    }
}

// ---------------------------------------------------------------------------
// Prep 2: x fp32 -> bf16, zero h0, zero flags
// (visibility to the coherent readers is guaranteed by the dispatch-boundary
//  L2 flush between this kernel and lstm_persist)
// ---------------------------------------------------------------------------
__global__ __launch_bounds__(256) void prep_x(const float* __restrict__ x,
                                              unsigned short* __restrict__ xb,
                                              unsigned short* __restrict__ h0,
                                              unsigned int* __restrict__ flags) {
    int gid = blockIdx.x * blockDim.x + threadIdx.x;
    int stride = gridDim.x * blockDim.x;
    const int N4 = BATCH * SEQ * INDIM / 4;
    const float4* xv = reinterpret_cast<const float4*>(x);
    uint2* xo = reinterpret_cast<uint2*>(xb);
    for (int i = gid; i < N4; i += stride) {
        float4 v = xv[i];
        uint2 o;
        o.x = (unsigned)f2bf(v.x) | ((unsigned)f2bf(v.y) << 16);
        o.y = (unsigned)f2bf(v.z) | ((unsigned)f2bf(v.w) << 16);
        xo[i] = o;
    }
    const int NH = BATCH * HID;
    for (int i = gid; i < NH; i += stride) h0[i] = 0;
    for (int i = gid; i < 256 * 64; i += stride) flags[i] = 0;  // 256 slots x 256B
}

// ---------------------------------------------------------------------------
// Persistent LSTM, fence-free coherent sync.
// 256 WGs x 256 thr; WG=(bg,ns): rows bg*16..+16, h-cols ns*32..+32, 4 gates.
// B-fragments register-resident. Per-producer flags (256B padded), relaxed
// agent atomics only. h exchanged via L3 (sc0|sc1 relaxed atomic ld/st).
// ---------------------------------------------------------------------------
__global__ __launch_bounds__(256, 1) void lstm_persist(
    const unsigned short* __restrict__ xb,   // [B][S][INDIM] bf16
    const unsigned short* __restrict__ WT,   // [NGATE][KTOT] bf16
    unsigned short* __restrict__ h0,         // [B][HID] bf16 (zeroed)
    unsigned short* __restrict__ h1,         // [B][HID] bf16
    unsigned int* __restrict__ flags,        // [NBG*NSL] x 64 uints (zeroed)
    const float* __restrict__ bias) {        // [NGATE]

    __shared__ unsigned short xbuf[2][XKK * 512];  // 2 x 8 KB, swizzled slots
    __shared__ unsigned short hbuf[HKK * 512];     // 32 KB, swizzled slots
    __shared__ float gex[4 * ROWS * JCOLS];        // 8 KB

    const int tid  = threadIdx.x;
    const int wave = tid >> 6, lane = tid & 63;
    const int lr = lane & 15, kq = lane >> 4;
    const int bg = blockIdx.x & 7;
    const int ns = blockIdx.x >> 3;
    const int b0 = bg * ROWS;
    const int j0 = ns * JCOLS;

    // ---- B fragments into registers (gate=wave, cols j0..j0+31, full K) ----
    s16x8 b0r[NKK], b1r[NKK];
    {
        const unsigned short* base0 =
            WT + ((size_t)(wave * HID + j0 + lr)) * KTOT + kq * 8;
        const unsigned short* base1 = base0 + (size_t)16 * KTOT;
#pragma unroll
        for (int kk = 0; kk < NKK; kk++) {
            b0r[kk] = *reinterpret_cast<const s16x8*>(base0 + kk * 32);
            b1r[kk] = *reinterpret_cast<const s16x8*>(base1 + kk * 32);
        }
    }

    // ---- epilogue constants ----
    const int ecol = tid & 31, erow0 = tid >> 5, erow1 = erow0 + 8;
    const int j = j0 + ecol;
    const float bf = bias[0 * HID + j], bi = bias[1 * HID + j],
                bgg = bias[2 * HID + j], bo = bias[3 * HID + j];
    float c0 = 0.f, c1 = 0.f;

    // ---- staging addressing ----
    // x stage (global_load_lds): lane s -> row s>>2, kq ((s&3)-(s>>3))&3
    const int srow = lane >> 2;
    const int skq = ((lane & 3) - ((lane >> 3) & 3)) & 3;
    const unsigned short* xsrc =
        xb + (size_t)(b0 + srow) * SEQ * INDIM + skq * 8;
    // MFMA A-read slot for this lane
    const int p_l = lr * 4 + ((kq + (lr >> 1)) & 3);

    unsigned int* myflag = flags + (size_t)(bg * NSL + ns) * 64;

    // ---- prologue: stage x for t=0 ----
#pragma unroll
    for (int q = 0; q < 2; q++) {
        int kk = 2 * wave + q;
        __builtin_amdgcn_global_load_lds(
            (const __attribute__((address_space(1))) void*)(xsrc + (size_t)0 * INDIM + kk * 32),
            (__attribute__((address_space(3))) void*)(&xbuf[0][kk * 512]),
            16, 0, 0);
    }
    __syncthreads();

    for (int t = 0; t < SEQ; t++) {
        const unsigned short* hin = (t & 1) ? h1 : h0;
        unsigned short* hout      = (t & 1) ? h0 : h1;
        const int par = t & 1;

        // ---- x-part MFMA (no dependence on other WGs) ----
        f32x4 acc0 = {0.f, 0.f, 0.f, 0.f};
        f32x4 acc1 = {0.f, 0.f, 0.f, 0.f};
        {
            const unsigned short* ax = &xbuf[par][p_l * 8];
#pragma unroll
            for (int kk = 0; kk < XKK; kk++) {
                s16x8 a = *reinterpret_cast<const s16x8*>(ax + kk * 512);
                acc0 = __builtin_amdgcn_mfma_f32_16x16x32_bf16(a, b0r[kk], acc0, 0, 0, 0);
                acc1 = __builtin_amdgcn_mfma_f32_16x16x32_bf16(a, b1r[kk], acc1, 0, 0, 0);
            }
        }

        // ---- fire-and-forget: stage x for t+1 into other parity buffer ----
        if (t + 1 < SEQ) {
#pragma unroll
            for (int q = 0; q < 2; q++) {
                int kk = 2 * wave + q;
                __builtin_amdgcn_global_load_lds(
                    (const __attribute__((address_space(1))) void*)(xsrc + (size_t)(t + 1) * INDIM + kk * 32),
                    (__attribute__((address_space(3))) void*)(&xbuf[par ^ 1][kk * 512]),
                    16, 0, 0);
            }
        }

        // ---- wait for all 32 producers of this group to publish h_t ----
        if (tid < NSL) {
            const unsigned int* fp = flags + (size_t)(bg * NSL + tid) * 64;
            while (__hip_atomic_load(fp, __ATOMIC_RELAXED,
                                     __HIP_MEMORY_SCOPE_AGENT) < (unsigned)t) {
                __builtin_amdgcn_s_sleep(1);
            }
        }
        asm volatile("" ::: "memory");
        __syncthreads();   // B1: flags satisfied for whole WG

        // ---- coherent h loads (L3) -> swizzled LDS ----
        {
            unsigned long long hv[16];
#pragma unroll
            for (int i = 0; i < 16; i++) {
                int u = tid + 256 * i;
                int kkh = u >> 7, v = u & 127, row = v >> 3, k8 = v & 7;
                const unsigned long long* gp = (const unsigned long long*)
                    (hin + (size_t)(b0 + row) * HID + kkh * 32 + k8 * 4);
                hv[i] = __hip_atomic_load(gp, __ATOMIC_RELAXED,
                                          __HIP_MEMORY_SCOPE_AGENT);
            }
#pragma unroll
            for (int i = 0; i < 16; i++) {
                int u = tid + 256 * i;
                int kkh = u >> 7, v = u & 127, row = v >> 3, k8 = v & 7;
                int kqh = k8 >> 1;
                int p = row * 4 + ((kqh + (row >> 1)) & 3);
                *(unsigned long long*)((char*)hbuf + kkh * 1024 + p * 16 + (k8 & 1) * 8) = hv[i];
            }
        }
        __syncthreads();   // B2: hbuf ready

        // ---- h-part MFMA ----
        {
            const unsigned short* ah = &hbuf[p_l * 8];
#pragma unroll
            for (int kk = 0; kk < HKK; kk++) {
                s16x8 a = *reinterpret_cast<const s16x8*>(ah + kk * 512);
                acc0 = __builtin_amdgcn_mfma_f32_16x16x32_bf16(a, b0r[XKK + kk], acc0, 0, 0, 0);
                acc1 = __builtin_amdgcn_mfma_f32_16x16x32_bf16(a, b1r[XKK + kk], acc1, 0, 0, 0);
            }
        }

        // ---- gate exchange (C/D: col=lane&15, row=(lane>>4)*4+r) ----
#pragma unroll
        for (int r = 0; r < 4; r++) {
            int row = kq * 4 + r;
            gex[wave * 512 + row * 32 + lr]      = acc0[r];
            gex[wave * 512 + row * 32 + 16 + lr] = acc1[r];
        }
        __syncthreads();   // B3: gex ready

        // ---- activations + c update + coherent h stores ----
        {
            float ff = sigmoidf_(gex[0 * 512 + erow0 * 32 + ecol] + bf);
            float ii = sigmoidf_(gex[1 * 512 + erow0 * 32 + ecol] + bi);
            float gg = tanhf_(gex[2 * 512 + erow0 * 32 + ecol] + bgg);
            float oo = sigmoidf_(gex[3 * 512 + erow0 * 32 + ecol] + bo);
            c0 = ff * c0 + ii * gg;
            __hip_atomic_store(hout + (size_t)(b0 + erow0) * HID + j,
                               f2bf(oo * tanhf_(c0)),
                               __ATOMIC_RELAXED, __HIP_MEMORY_SCOPE_AGENT);
        }
        {
            float ff = sigmoidf_(gex[0 * 512 + erow1 * 32 + ecol] + bf);
            float ii = sigmoidf_(gex[1 * 512 + erow1 * 32 + ecol] + bi);
            float gg = tanhf_(gex[2 * 512 + erow1 * 32 + ecol] + bgg);
            float oo = sigmoidf_(gex[3 * 512 + erow1 * 32 + ecol] + bo);
            c1 = ff * c1 + ii * gg;
            __hip_atomic_store(hout + (size_t)(b0 + erow1) * HID + j,
                               f2bf(oo * tanhf_(c1)),
                               __ATOMIC_RELAXED, __HIP_MEMORY_SCOPE_AGENT);
        }

        __syncthreads();   // B4: every wave's stores drained (vmcnt(0)) + gex free
        asm volatile("" ::: "memory");
        if (tid == 0) {
            __hip_atomic_store(myflag, (unsigned)(t + 1),
                               __ATOMIC_RELAXED, __HIP_MEMORY_SCOPE_AGENT);
        }
    }
}

// ---------------------------------------------------------------------------
// Final FC
// ---------------------------------------------------------------------------
__global__ __launch_bounds__(256) void final_fc(const unsigned short* __restrict__ h,
                                                const float* __restrict__ Wfc,
                                                const float* __restrict__ bfc,
                                                float* __restrict__ out) {
    int b = blockIdx.x;
    int o = threadIdx.x;
    const unsigned short* hr = h + (size_t)b * HID;
    float acc = bfc[o];
#pragma unroll 8
    for (int k = 0; k < HID; k++) {
        acc += __uint_as_float(((unsigned)hr[k]) << 16) * Wfc[(size_t)k * OUTD + o];
    }
    out[(size_t)b * OUTD + o] = acc;
}

// ---------------------------------------------------------------------------
extern "C" void kernel_launch(void* const* d_in, const int* in_sizes, int n_in,
                              void* d_out, int out_size, void* d_ws, size_t ws_size,
                              hipStream_t stream) {
    const float* x    = (const float*)d_in[0];
    const float* Wx   = (const float*)d_in[1];
    const float* Wh   = (const float*)d_in[2];
    const float* bias = (const float*)d_in[3];
    const float* Wfc  = (const float*)d_in[4];
    const float* bfc  = (const float*)d_in[5];
    float* out = (float*)d_out;

    char* ws = (char*)d_ws;
    // ws layout (bytes):
    //   WT    : 4096*1280*2    = 10,485,760  @ 0
    //   xb    : 128*1024*256*2 = 67,108,864  @ 10,485,760
    //   h0    : 128*1024*2     =    262,144  @ 77,594,624
    //   h1    : 128*1024*2     =    262,144  @ 77,856,768
    //   flags : 256*64*4       =     65,536  @ 78,118,912
    unsigned short* WT  = (unsigned short*)(ws);
    unsigned short* xb  = (unsigned short*)(ws + 10485760);
    unsigned short* h0  = (unsigned short*)(ws + 77594624);
    unsigned short* h1  = (unsigned short*)(ws + 77856768);
    unsigned int* flags = (unsigned int*)(ws + 78118912);

    hipLaunchKernelGGL(prep_wt, dim3(KTOT / 64, NGATE / 64), dim3(256), 0, stream,
                       Wx, Wh, WT);
    hipLaunchKernelGGL(prep_x, dim3(1024), dim3(256), 0, stream, x, xb, h0, flags);

    hipLaunchKernelGGL(lstm_persist, dim3(256), dim3(256), 0, stream,
                       xb, WT, h0, h1, flags, bias);

    // 1024 steps -> final h lands in h0
    hipLaunchKernelGGL(final_fc, dim3(128), dim3(256), 0, stream, h0, Wfc, bfc, out);
}